// Round 7
// baseline (103.357 us; speedup 1.0000x reference)
//
#include <hip/hip_runtime.h>
#include <hip/hip_bf16.h>

// GraphLSTM fused kernel for MI355X — R6: DENSE-READ experiment (R5 compile fix:
// asm keep-alive sinks take scalar components, not float4).
// Theory under test: the periodic f-gate holes (25% of every 8KB W block,
// 25% of every 1KB bias block) skip the SAME channel slots every edge ->
// fixed fraction of DRAM channels idle -> ~75% BW cap. Read dense (+86 MB)
// with no-op keep-alives placed after compute (no added stalls).

#define MN 1024
#define BB 8

__device__ __forceinline__ float fsig(float x) {
    return __builtin_amdgcn_rcpf(1.0f + __expf(-x));
}
__device__ __forceinline__ float ftanh(float x) {
    float t = fminf(fmaxf(2.0f * x, -30.0f), 30.0f);   // avoid inf/inf
    float e = __expf(t);
    return (e - 1.0f) * __builtin_amdgcn_rcpf(e + 1.0f);
}
__device__ __forceinline__ float rl(float v, int idx) {
    return __int_as_float(__builtin_amdgcn_readlane(__float_as_int(v), idx));
}

// Prep: transpose x (B,D,MN) -> xt (MN,B,D) and init out = conv_b.
__global__ void prep_kernel(const float* __restrict__ x,
                            const float* __restrict__ conv_b,
                            float* __restrict__ xt,
                            float* __restrict__ out) {
    int tid = blockIdx.x * 256 + threadIdx.x;   // 65536 threads
    if (tid < MN * BB * 8) {
        int mn = tid >> 6;
        int b  = (tid >> 3) & 7;
        int d  = tid & 7;
        xt[tid] = x[b * (8 * MN) + d * MN + mn];
    }
    if (tid < BB * MN) out[tid] = conv_b[0];
}

struct WRegs {
    float4 wi0, wi1, wg0, wg1, wo0, wo1;   // 24 VGPR (used)
    float4 wf0, wf1;                        // 8 VGPR (dense-read filler)
    float  bIi, bIh, bGi, bGh, bOi, bOh;   // 6 VGPR
    float  bFi, bFh;                        // 2 VGPR (dense-read filler)
};

__device__ __forceinline__ void loadW(WRegs& r, int e, int lane,
        const float* __restrict__ W, const float* __restrict__ b_ih,
        const float* __restrict__ b_hh) {
    const float* We = W + (size_t)e * 2048 + lane * 8;
    r.wi0 = *(const float4*)(We);
    r.wi1 = *(const float4*)(We + 4);
    r.wf0 = *(const float4*)(We + 512);    // f-gate chunk: dense stream filler
    r.wf1 = *(const float4*)(We + 516);
    r.wg0 = *(const float4*)(We + 1024);
    r.wg1 = *(const float4*)(We + 1028);
    r.wo0 = *(const float4*)(We + 1536);
    r.wo1 = *(const float4*)(We + 1540);
    const float* bi = b_ih + (size_t)e * 256 + lane;
    const float* bh = b_hh + (size_t)e * 256 + lane;
    r.bIi = bi[0];   r.bIh = bh[0];
    r.bFi = bi[64];  r.bFh = bh[64];       // f-bias granule: dense filler
    r.bGi = bi[128]; r.bGh = bh[128];
    r.bOi = bi[192]; r.bOh = bh[192];
}

__device__ __forceinline__ void computeEdge(const WRegs& r, float xreg,
        int dst, float ew, float cw, float* __restrict__ out, int lane) {
    float bI = r.bIi + r.bIh;
    float bG = r.bGi + r.bGh;
    float bO = r.bOi + r.bOh;
    float s[BB];
#pragma unroll
    for (int b = 0; b < BB; ++b) {
        float x0 = rl(xreg, b * 8 + 0), x1 = rl(xreg, b * 8 + 1);
        float x2 = rl(xreg, b * 8 + 2), x3 = rl(xreg, b * 8 + 3);
        float x4 = rl(xreg, b * 8 + 4), x5 = rl(xreg, b * 8 + 5);
        float x6 = rl(xreg, b * 8 + 6), x7 = rl(xreg, b * 8 + 7);
        float pi = bI, pg = bG, po = bO;
        pi = fmaf(r.wi0.x, x0, pi); pg = fmaf(r.wg0.x, x0, pg); po = fmaf(r.wo0.x, x0, po);
        pi = fmaf(r.wi0.y, x1, pi); pg = fmaf(r.wg0.y, x1, pg); po = fmaf(r.wo0.y, x1, po);
        pi = fmaf(r.wi0.z, x2, pi); pg = fmaf(r.wg0.z, x2, pg); po = fmaf(r.wo0.z, x2, po);
        pi = fmaf(r.wi0.w, x3, pi); pg = fmaf(r.wg0.w, x3, pg); po = fmaf(r.wo0.w, x3, po);
        pi = fmaf(r.wi1.x, x4, pi); pg = fmaf(r.wg1.x, x4, pg); po = fmaf(r.wo1.x, x4, po);
        pi = fmaf(r.wi1.y, x5, pi); pg = fmaf(r.wg1.y, x5, pg); po = fmaf(r.wo1.y, x5, po);
        pi = fmaf(r.wi1.z, x6, pi); pg = fmaf(r.wg1.z, x6, pg); po = fmaf(r.wo1.z, x6, po);
        pi = fmaf(r.wi1.w, x7, pi); pg = fmaf(r.wg1.w, x7, pg); po = fmaf(r.wo1.w, x7, po);
        float c = fsig(pi) * ftanh(pg);
        float h = fsig(po) * ftanh(c);
        s[b] = cw * h;
    }
    // Batch-folding reduction over 64 lanes (Σ_h), 10 shuffles total.
    float u[4];
#pragma unroll
    for (int k = 0; k < 4; ++k) {
        float keep = (lane & 32) ? s[k + 4] : s[k];
        float send = (lane & 32) ? s[k]     : s[k + 4];
        u[k] = keep + __shfl_xor(send, 32, 64);
    }
    float v[2];
#pragma unroll
    for (int k = 0; k < 2; ++k) {
        float keep = (lane & 16) ? u[k + 2] : u[k];
        float send = (lane & 16) ? u[k]     : u[k + 2];
        v[k] = keep + __shfl_xor(send, 16, 64);
    }
    float keep = (lane & 8) ? v[1] : v[0];
    float send = (lane & 8) ? v[0] : v[1];
    float t = keep + __shfl_xor(send, 8, 64);
    t += __shfl_xor(t, 4, 64);
    t += __shfl_xor(t, 2, 64);
    t += __shfl_xor(t, 1, 64);
    if ((lane & 7) == 0) {
        int b = lane >> 3;
        atomicAdd(out + b * MN + dst, ew * t);
    }
    // Keep the dense-read filler loads alive WITHOUT using their values.
    // Scalar components only (float4 hits "indirect register inputs" error).
    asm volatile("" :: "v"(r.wf0.x), "v"(r.wf0.y), "v"(r.wf0.z), "v"(r.wf0.w),
                       "v"(r.wf1.x), "v"(r.wf1.y), "v"(r.wf1.z), "v"(r.wf1.w),
                       "v"(r.bFi), "v"(r.bFh));
}

__global__ __launch_bounds__(256, 4) void edge_kernel(
        const float* __restrict__ xt,      // (MN, B, D)
        const float* __restrict__ edge_w,  // (E)
        const float* __restrict__ W,       // (E, 256, 8)
        const float* __restrict__ b_ih,    // (E, 256)
        const float* __restrict__ b_hh,    // (E, 256)
        const float* __restrict__ conv_w,  // (1, 64)
        const int*   __restrict__ src_idx,
        const int*   __restrict__ dst_idx,
        float* __restrict__ out,           // (B, MN), pre-initialized to conv_b
        int E) {
    int lane = threadIdx.x & 63;
    int nw = gridDim.x * 4;
    int e0 = __builtin_amdgcn_readfirstlane(blockIdx.x * 4 + (threadIdx.x >> 6));
    if (e0 >= E) return;
    float cw = conv_w[lane];

    int eC = e0, eN = e0 + nw, eN2 = eN + nw;

    int   srcC = src_idx[eC], dstC = dst_idx[eC];
    float ewC  = edge_w[eC];
    int srcN = 0, dstN = 0; float ewN = 0.0f;
    if (eN < E) { srcN = src_idx[eN]; dstN = dst_idx[eN]; ewN = edge_w[eN]; }

    WRegs A, B;
    loadW(A, eC, lane, W, b_ih, b_hh);
    float xA = xt[(size_t)srcC * 64 + lane];
    float xB = 0.0f;
    bool useA = true;

    while (true) {
        bool hasN  = (eN  < E);
        bool hasN2 = (eN2 < E);
        int srcN2 = 0, dstN2 = 0; float ewN2 = 0.0f;
        if (hasN2) { srcN2 = src_idx[eN2]; dstN2 = dst_idx[eN2]; ewN2 = edge_w[eN2]; }

        // Prefetch W + x for edge N (srcN s_loaded last iteration — no wait).
        if (hasN) {
            if (useA) { loadW(B, eN, lane, W, b_ih, b_hh);
                        xB = xt[(size_t)srcN * 64 + lane]; }
            else      { loadW(A, eN, lane, W, b_ih, b_hh);
                        xA = xt[(size_t)srcN * 64 + lane]; }
        }
        __builtin_amdgcn_sched_barrier(0);

        // Compute edge C — operands arrived during previous compute.
        if (useA) computeEdge(A, xA, dstC, ewC, cw, out, lane);
        else      computeEdge(B, xB, dstC, ewC, cw, out, lane);

        if (!hasN) break;
        srcC = srcN; dstC = dstN; ewC = ewN;
        srcN = srcN2; dstN = dstN2; ewN = ewN2;
        eC = eN; eN = eN2; eN2 += nw;
        useA = !useA;
    }
}

extern "C" void kernel_launch(void* const* d_in, const int* in_sizes, int n_in,
                              void* d_out, int out_size, void* d_ws, size_t ws_size,
                              hipStream_t stream) {
    const float* x      = (const float*)d_in[0];
    const float* edge_w = (const float*)d_in[1];
    const float* W_ih   = (const float*)d_in[2];
    const float* b_ih   = (const float*)d_in[3];
    const float* b_hh   = (const float*)d_in[4];
    const float* conv_w = (const float*)d_in[5];
    const float* conv_b = (const float*)d_in[6];
    const int* src_idx  = (const int*)d_in[7];
    const int* dst_idx  = (const int*)d_in[8];
    int E = in_sizes[1];

    float* xt  = (float*)d_ws;      // 65536 floats = 256 KB
    float* out = (float*)d_out;     // 8192 floats

    prep_kernel<<<256, 256, 0, stream>>>(x, conv_b, xt, out);

    // Persistent grid: 4 blocks/CU x 256 CUs = 16 waves/CU.
    edge_kernel<<<1024, 256, 0, stream>>>(xt, edge_w, W_ih, b_ih, b_hh,
                                          conv_w, src_idx, dst_idx, out, E);
}

// Round 8
// 73.349 us; speedup vs baseline: 1.4091x; 1.4091x over previous
//
#include <hip/hip_runtime.h>
#include <hip/hip_bf16.h>

// GraphLSTM fused kernel for MI355X — R7: memory-stream shape fixes.
//  vs R4 (71.8us): (1) chunked (contiguous) edge ranges per persistent wave
//  instead of stride-4096 — consecutive edge bursts continue in the same DRAM
//  rows (66KB contiguous per wave) instead of jumping 32MB; (2) non-temporal
//  loads for the single-use W/bias streams (bypass L1, free miss slots).
//  Schedule, occupancy (4 waves/SIMD), and byte count unchanged vs R4.

#define MN 1024
#define BB 8

typedef float vf4 __attribute__((ext_vector_type(4)));

__device__ __forceinline__ float fsig(float x) {
    return __builtin_amdgcn_rcpf(1.0f + __expf(-x));
}
__device__ __forceinline__ float ftanh(float x) {
    float t = fminf(fmaxf(2.0f * x, -30.0f), 30.0f);   // avoid inf/inf
    float e = __expf(t);
    return (e - 1.0f) * __builtin_amdgcn_rcpf(e + 1.0f);
}
__device__ __forceinline__ float rl(float v, int idx) {
    return __int_as_float(__builtin_amdgcn_readlane(__float_as_int(v), idx));
}

// Prep: transpose x (B,D,MN) -> xt (MN,B,D) and init out = conv_b.
__global__ void prep_kernel(const float* __restrict__ x,
                            const float* __restrict__ conv_b,
                            float* __restrict__ xt,
                            float* __restrict__ out) {
    int tid = blockIdx.x * 256 + threadIdx.x;   // 65536 threads
    if (tid < MN * BB * 8) {
        int mn = tid >> 6;
        int b  = (tid >> 3) & 7;
        int d  = tid & 7;
        xt[tid] = x[b * (8 * MN) + d * MN + mn];
    }
    if (tid < BB * MN) out[tid] = conv_b[0];
}

struct WRegs {
    vf4   wi0, wi1, wg0, wg1, wo0, wo1;    // 24 VGPR
    float bIi, bIh, bGi, bGh, bOi, bOh;    // 6 VGPR
};

__device__ __forceinline__ void loadW(WRegs& r, int e, int lane,
        const float* __restrict__ W, const float* __restrict__ b_ih,
        const float* __restrict__ b_hh) {
    const float* We = W + (size_t)e * 2048 + lane * 8;
    r.wi0 = __builtin_nontemporal_load((const vf4*)(We));
    r.wi1 = __builtin_nontemporal_load((const vf4*)(We + 4));
    r.wg0 = __builtin_nontemporal_load((const vf4*)(We + 1024));
    r.wg1 = __builtin_nontemporal_load((const vf4*)(We + 1028));
    r.wo0 = __builtin_nontemporal_load((const vf4*)(We + 1536));
    r.wo1 = __builtin_nontemporal_load((const vf4*)(We + 1540));
    const float* bi = b_ih + (size_t)e * 256 + lane;
    const float* bh = b_hh + (size_t)e * 256 + lane;
    r.bIi = __builtin_nontemporal_load(bi);
    r.bIh = __builtin_nontemporal_load(bh);
    r.bGi = __builtin_nontemporal_load(bi + 128);
    r.bGh = __builtin_nontemporal_load(bh + 128);
    r.bOi = __builtin_nontemporal_load(bi + 192);
    r.bOh = __builtin_nontemporal_load(bh + 192);
}

__device__ __forceinline__ void computeEdge(const WRegs& r, float xreg,
        int dst, float ew, float cw, float* __restrict__ out, int lane) {
    float bI = r.bIi + r.bIh;
    float bG = r.bGi + r.bGh;
    float bO = r.bOi + r.bOh;
    float s[BB];
#pragma unroll
    for (int b = 0; b < BB; ++b) {
        float x0 = rl(xreg, b * 8 + 0), x1 = rl(xreg, b * 8 + 1);
        float x2 = rl(xreg, b * 8 + 2), x3 = rl(xreg, b * 8 + 3);
        float x4 = rl(xreg, b * 8 + 4), x5 = rl(xreg, b * 8 + 5);
        float x6 = rl(xreg, b * 8 + 6), x7 = rl(xreg, b * 8 + 7);
        float pi = bI, pg = bG, po = bO;
        pi = fmaf(r.wi0[0], x0, pi); pg = fmaf(r.wg0[0], x0, pg); po = fmaf(r.wo0[0], x0, po);
        pi = fmaf(r.wi0[1], x1, pi); pg = fmaf(r.wg0[1], x1, pg); po = fmaf(r.wo0[1], x1, po);
        pi = fmaf(r.wi0[2], x2, pi); pg = fmaf(r.wg0[2], x2, pg); po = fmaf(r.wo0[2], x2, po);
        pi = fmaf(r.wi0[3], x3, pi); pg = fmaf(r.wg0[3], x3, pg); po = fmaf(r.wo0[3], x3, po);
        pi = fmaf(r.wi1[0], x4, pi); pg = fmaf(r.wg1[0], x4, pg); po = fmaf(r.wo1[0], x4, po);
        pi = fmaf(r.wi1[1], x5, pi); pg = fmaf(r.wg1[1], x5, pg); po = fmaf(r.wo1[1], x5, po);
        pi = fmaf(r.wi1[2], x6, pi); pg = fmaf(r.wg1[2], x6, pg); po = fmaf(r.wo1[2], x6, po);
        pi = fmaf(r.wi1[3], x7, pi); pg = fmaf(r.wg1[3], x7, pg); po = fmaf(r.wo1[3], x7, po);
        float c = fsig(pi) * ftanh(pg);
        float h = fsig(po) * ftanh(c);
        s[b] = cw * h;
    }
    // Batch-folding reduction over 64 lanes (Σ_h), 10 shuffles total.
    float u[4];
#pragma unroll
    for (int k = 0; k < 4; ++k) {
        float keep = (lane & 32) ? s[k + 4] : s[k];
        float send = (lane & 32) ? s[k]     : s[k + 4];
        u[k] = keep + __shfl_xor(send, 32, 64);
    }
    float v[2];
#pragma unroll
    for (int k = 0; k < 2; ++k) {
        float keep = (lane & 16) ? u[k + 2] : u[k];
        float send = (lane & 16) ? u[k]     : u[k + 2];
        v[k] = keep + __shfl_xor(send, 16, 64);
    }
    float keep = (lane & 8) ? v[1] : v[0];
    float send = (lane & 8) ? v[0] : v[1];
    float t = keep + __shfl_xor(send, 8, 64);
    t += __shfl_xor(t, 4, 64);
    t += __shfl_xor(t, 2, 64);
    t += __shfl_xor(t, 1, 64);
    if ((lane & 7) == 0) {
        int b = lane >> 3;
        atomicAdd(out + b * MN + dst, ew * t);
    }
}

__global__ __launch_bounds__(256, 4) void edge_kernel(
        const float* __restrict__ xt,      // (MN, B, D)
        const float* __restrict__ edge_w,  // (E)
        const float* __restrict__ W,       // (E, 256, 8)
        const float* __restrict__ b_ih,    // (E, 256)
        const float* __restrict__ b_hh,    // (E, 256)
        const float* __restrict__ conv_w,  // (1, 64)
        const int*   __restrict__ src_idx,
        const int*   __restrict__ dst_idx,
        float* __restrict__ out,           // (B, MN), pre-initialized to conv_b
        int E) {
    int lane = threadIdx.x & 63;
    int nW = gridDim.x * 4;
    int wid = __builtin_amdgcn_readfirstlane(blockIdx.x * 4 + (threadIdx.x >> 6));
    // Contiguous chunk of edges for this wave (DRAM row locality).
    int eC  = (int)((long long)wid * E / nW);
    int end = (int)((long long)(wid + 1) * E / nW);
    if (eC >= end) return;
    float cw = conv_w[lane];

    int eN = eC + 1, eN2 = eC + 2;

    int   srcC = src_idx[eC], dstC = dst_idx[eC];
    float ewC  = edge_w[eC];
    int srcN = 0, dstN = 0; float ewN = 0.0f;
    if (eN < end) { srcN = src_idx[eN]; dstN = dst_idx[eN]; ewN = edge_w[eN]; }

    WRegs A, B;
    loadW(A, eC, lane, W, b_ih, b_hh);
    float xA = xt[(size_t)srcC * 64 + lane];
    float xB = 0.0f;
    bool useA = true;

    while (true) {
        bool hasN  = (eN  < end);
        bool hasN2 = (eN2 < end);
        int srcN2 = 0, dstN2 = 0; float ewN2 = 0.0f;
        if (hasN2) { srcN2 = src_idx[eN2]; dstN2 = dst_idx[eN2]; ewN2 = edge_w[eN2]; }

        // Prefetch W + x for edge N (srcN s_loaded last iteration — no wait).
        if (hasN) {
            if (useA) { loadW(B, eN, lane, W, b_ih, b_hh);
                        xB = xt[(size_t)srcN * 64 + lane]; }
            else      { loadW(A, eN, lane, W, b_ih, b_hh);
                        xA = xt[(size_t)srcN * 64 + lane]; }
        }
        __builtin_amdgcn_sched_barrier(0);

        // Compute edge C — operands arrived during previous compute.
        if (useA) computeEdge(A, xA, dstC, ewC, cw, out, lane);
        else      computeEdge(B, xB, dstC, ewC, cw, out, lane);

        if (!hasN) break;
        srcC = srcN; dstC = dstN; ewC = ewN;
        srcN = srcN2; dstN = dstN2; ewN = ewN2;
        eC = eN; eN = eN2; eN2 += 1;
        useA = !useA;
    }
}

extern "C" void kernel_launch(void* const* d_in, const int* in_sizes, int n_in,
                              void* d_out, int out_size, void* d_ws, size_t ws_size,
                              hipStream_t stream) {
    const float* x      = (const float*)d_in[0];
    const float* edge_w = (const float*)d_in[1];
    const float* W_ih   = (const float*)d_in[2];
    const float* b_ih   = (const float*)d_in[3];
    const float* b_hh   = (const float*)d_in[4];
    const float* conv_w = (const float*)d_in[5];
    const float* conv_b = (const float*)d_in[6];
    const int* src_idx  = (const int*)d_in[7];
    const int* dst_idx  = (const int*)d_in[8];
    int E = in_sizes[1];

    float* xt  = (float*)d_ws;      // 65536 floats = 256 KB
    float* out = (float*)d_out;     // 8192 floats

    prep_kernel<<<256, 256, 0, stream>>>(x, conv_b, xt, out);

    // Persistent grid: 4 blocks/CU x 256 CUs = 16 waves/CU.
    edge_kernel<<<1024, 256, 0, stream>>>(xt, edge_w, W_ih, b_ih, b_hh,
                                          conv_w, src_idx, dst_idx, out, E);
}

// Round 9
// 63.654 us; speedup vs baseline: 1.6237x; 1.1523x over previous
//
#include <hip/hip_runtime.h>
#include <hip/hip_bf16.h>

// GraphLSTM fused kernel for MI355X — R8: privatized atomic spread (x32).
// R2-R7 flat at ~72us across every READ-side knob -> suspect the write side:
// 34.8K atomic instrs land on only 512 cachelines from all 8 XCDs (device-
// scope, cross-XCD serialization ~543 same-line ops). This round: atomics go
// to 32 privatized copies in d_ws (conflicts /32), tiny reduce kernel sums
// copies + conv_b into d_out. Read path identical to R4 (71.8us baseline).

#define MN 1024
#define BB 8
#define NCOPY 32

__device__ __forceinline__ float fsig(float x) {
    return __builtin_amdgcn_rcpf(1.0f + __expf(-x));
}
__device__ __forceinline__ float ftanh(float x) {
    float t = fminf(fmaxf(2.0f * x, -30.0f), 30.0f);   // avoid inf/inf
    float e = __expf(t);
    return (e - 1.0f) * __builtin_amdgcn_rcpf(e + 1.0f);
}
__device__ __forceinline__ float rl(float v, int idx) {
    return __int_as_float(__builtin_amdgcn_readlane(__float_as_int(v), idx));
}

// Prep: transpose x (B,D,MN) -> xt (MN,B,D); zero the 32 partial buffers.
__global__ void prep_kernel(const float* __restrict__ x,
                            float* __restrict__ xt,
                            float* __restrict__ partial) {
    int tid = blockIdx.x * 256 + threadIdx.x;   // 65536 threads
    if (tid < MN * BB * 8) {
        int mn = tid >> 6;
        int b  = (tid >> 3) & 7;
        int d  = tid & 7;
        xt[tid] = x[b * (8 * MN) + d * MN + mn];
    }
    // Zero 32 x 8192 floats (4 per thread), every launch (replay-safe).
    float4* p4 = (float4*)partial;
    p4[tid] = make_float4(0.f, 0.f, 0.f, 0.f);
}

// Reduce: out[t] = conv_b + sum_k partial[k][t].
__global__ void reduce_kernel(const float* __restrict__ partial,
                              const float* __restrict__ conv_b,
                              float* __restrict__ out) {
    int tid = blockIdx.x * 256 + threadIdx.x;   // 8192 threads
    float s = conv_b[0];
#pragma unroll
    for (int k = 0; k < NCOPY; ++k) s += partial[k * (BB * MN) + tid];
    out[tid] = s;
}

struct WRegs {
    float4 wi0, wi1, wg0, wg1, wo0, wo1;   // 24 VGPR
    float  bIi, bIh, bGi, bGh, bOi, bOh;   // 6 VGPR
};

__device__ __forceinline__ void loadW(WRegs& r, int e, int lane,
        const float* __restrict__ W, const float* __restrict__ b_ih,
        const float* __restrict__ b_hh) {
    const float* We = W + (size_t)e * 2048 + lane * 8;
    r.wi0 = *(const float4*)(We);
    r.wi1 = *(const float4*)(We + 4);
    r.wg0 = *(const float4*)(We + 1024);
    r.wg1 = *(const float4*)(We + 1028);
    r.wo0 = *(const float4*)(We + 1536);
    r.wo1 = *(const float4*)(We + 1540);
    const float* bi = b_ih + (size_t)e * 256 + lane;
    const float* bh = b_hh + (size_t)e * 256 + lane;
    r.bIi = bi[0];   r.bIh = bh[0];
    r.bGi = bi[128]; r.bGh = bh[128];
    r.bOi = bi[192]; r.bOh = bh[192];
}

__device__ __forceinline__ void computeEdge(const WRegs& r, float xreg,
        int dst, float ew, float cw, float* __restrict__ pout, int lane) {
    float bI = r.bIi + r.bIh;
    float bG = r.bGi + r.bGh;
    float bO = r.bOi + r.bOh;
    float s[BB];
#pragma unroll
    for (int b = 0; b < BB; ++b) {
        float x0 = rl(xreg, b * 8 + 0), x1 = rl(xreg, b * 8 + 1);
        float x2 = rl(xreg, b * 8 + 2), x3 = rl(xreg, b * 8 + 3);
        float x4 = rl(xreg, b * 8 + 4), x5 = rl(xreg, b * 8 + 5);
        float x6 = rl(xreg, b * 8 + 6), x7 = rl(xreg, b * 8 + 7);
        float pi = bI, pg = bG, po = bO;
        pi = fmaf(r.wi0.x, x0, pi); pg = fmaf(r.wg0.x, x0, pg); po = fmaf(r.wo0.x, x0, po);
        pi = fmaf(r.wi0.y, x1, pi); pg = fmaf(r.wg0.y, x1, pg); po = fmaf(r.wo0.y, x1, po);
        pi = fmaf(r.wi0.z, x2, pi); pg = fmaf(r.wg0.z, x2, pg); po = fmaf(r.wo0.z, x2, po);
        pi = fmaf(r.wi0.w, x3, pi); pg = fmaf(r.wg0.w, x3, pg); po = fmaf(r.wo0.w, x3, po);
        pi = fmaf(r.wi1.x, x4, pi); pg = fmaf(r.wg1.x, x4, pg); po = fmaf(r.wo1.x, x4, po);
        pi = fmaf(r.wi1.y, x5, pi); pg = fmaf(r.wg1.y, x5, pg); po = fmaf(r.wo1.y, x5, po);
        pi = fmaf(r.wi1.z, x6, pi); pg = fmaf(r.wg1.z, x6, pg); po = fmaf(r.wo1.z, x6, po);
        pi = fmaf(r.wi1.w, x7, pi); pg = fmaf(r.wg1.w, x7, pg); po = fmaf(r.wo1.w, x7, po);
        float c = fsig(pi) * ftanh(pg);
        float h = fsig(po) * ftanh(c);
        s[b] = cw * h;
    }
    // Batch-folding reduction over 64 lanes (Σ_h), 10 shuffles total.
    float u[4];
#pragma unroll
    for (int k = 0; k < 4; ++k) {
        float keep = (lane & 32) ? s[k + 4] : s[k];
        float send = (lane & 32) ? s[k]     : s[k + 4];
        u[k] = keep + __shfl_xor(send, 32, 64);
    }
    float v[2];
#pragma unroll
    for (int k = 0; k < 2; ++k) {
        float keep = (lane & 16) ? u[k + 2] : u[k];
        float send = (lane & 16) ? u[k]     : u[k + 2];
        v[k] = keep + __shfl_xor(send, 16, 64);
    }
    float keep = (lane & 8) ? v[1] : v[0];
    float send = (lane & 8) ? v[0] : v[1];
    float t = keep + __shfl_xor(send, 8, 64);
    t += __shfl_xor(t, 4, 64);
    t += __shfl_xor(t, 2, 64);
    t += __shfl_xor(t, 1, 64);
    if ((lane & 7) == 0) {
        int b = lane >> 3;
        atomicAdd(pout + b * MN + dst, ew * t);
    }
}

__global__ __launch_bounds__(256, 4) void edge_kernel(
        const float* __restrict__ xt,      // (MN, B, D)
        const float* __restrict__ edge_w,  // (E)
        const float* __restrict__ W,       // (E, 256, 8)
        const float* __restrict__ b_ih,    // (E, 256)
        const float* __restrict__ b_hh,    // (E, 256)
        const float* __restrict__ conv_w,  // (1, 64)
        const int*   __restrict__ src_idx,
        const int*   __restrict__ dst_idx,
        float* __restrict__ partial,       // (NCOPY, B, MN) zeroed by prep
        int E) {
    int lane = threadIdx.x & 63;
    int nw = gridDim.x * 4;
    int wid = blockIdx.x * 4 + (threadIdx.x >> 6);
    int e0 = __builtin_amdgcn_readfirstlane(wid);
    if (e0 >= E) return;
    float cw = conv_w[lane];
    // Privatized output copy for this wave (conflicts / 32).
    float* pout = partial + (size_t)(wid & (NCOPY - 1)) * (BB * MN);

    int eC = e0, eN = e0 + nw, eN2 = eN + nw;

    int   srcC = src_idx[eC], dstC = dst_idx[eC];
    float ewC  = edge_w[eC];
    int srcN = 0, dstN = 0; float ewN = 0.0f;
    if (eN < E) { srcN = src_idx[eN]; dstN = dst_idx[eN]; ewN = edge_w[eN]; }

    WRegs A, B;
    loadW(A, eC, lane, W, b_ih, b_hh);
    float xA = xt[(size_t)srcC * 64 + lane];
    float xB = 0.0f;
    bool useA = true;

    while (true) {
        bool hasN  = (eN  < E);
        bool hasN2 = (eN2 < E);
        int srcN2 = 0, dstN2 = 0; float ewN2 = 0.0f;
        if (hasN2) { srcN2 = src_idx[eN2]; dstN2 = dst_idx[eN2]; ewN2 = edge_w[eN2]; }

        // Prefetch W + x for edge N (srcN s_loaded last iteration — no wait).
        if (hasN) {
            if (useA) { loadW(B, eN, lane, W, b_ih, b_hh);
                        xB = xt[(size_t)srcN * 64 + lane]; }
            else      { loadW(A, eN, lane, W, b_ih, b_hh);
                        xA = xt[(size_t)srcN * 64 + lane]; }
        }
        __builtin_amdgcn_sched_barrier(0);

        // Compute edge C — operands arrived during previous compute.
        if (useA) computeEdge(A, xA, dstC, ewC, cw, pout, lane);
        else      computeEdge(B, xB, dstC, ewC, cw, pout, lane);

        if (!hasN) break;
        srcC = srcN; dstC = dstN; ewC = ewN;
        srcN = srcN2; dstN = dstN2; ewN = ewN2;
        eC = eN; eN = eN2; eN2 += nw;
        useA = !useA;
    }
}

extern "C" void kernel_launch(void* const* d_in, const int* in_sizes, int n_in,
                              void* d_out, int out_size, void* d_ws, size_t ws_size,
                              hipStream_t stream) {
    const float* x      = (const float*)d_in[0];
    const float* edge_w = (const float*)d_in[1];
    const float* W_ih   = (const float*)d_in[2];
    const float* b_ih   = (const float*)d_in[3];
    const float* b_hh   = (const float*)d_in[4];
    const float* conv_w = (const float*)d_in[5];
    const float* conv_b = (const float*)d_in[6];
    const int* src_idx  = (const int*)d_in[7];
    const int* dst_idx  = (const int*)d_in[8];
    int E = in_sizes[1];

    float* xt      = (float*)d_ws;             // 65536 floats = 256 KB
    float* partial = (float*)d_ws + 65536;     // 32 x 8192 floats = 1 MB
    float* out     = (float*)d_out;            // 8192 floats

    prep_kernel<<<256, 256, 0, stream>>>(x, xt, partial);

    // Persistent grid: 4 blocks/CU x 256 CUs = 16 waves/CU.
    edge_kernel<<<1024, 256, 0, stream>>>(xt, edge_w, W_ih, b_ih, b_hh,
                                          conv_w, src_idx, dst_idx, partial, E);

    reduce_kernel<<<32, 256, 0, stream>>>(partial, conv_b, out);
}